// Round 5
// baseline (319.235 us; speedup 1.0000x reference)
//
#include <hip/hip_runtime.h>
#include <hip/hip_bf16.h>

#define BB 16
#define TT 2048
#define DIMC 512
#define HEADH 64

typedef __attribute__((ext_vector_type(8))) short short8v;   // 8 bf16 (4 VGPRs)
typedef __attribute__((ext_vector_type(4))) float f32x4;     // MFMA C/D

static __device__ __forceinline__ unsigned short f2bf(float f) {
    __hip_bfloat16 h = __float2bfloat16(f);          // RNE, native path
    unsigned short u;
    __builtin_memcpy(&u, &h, 2);
    return u;
}
static __device__ __forceinline__ unsigned int packbf(float lo, float hi) {
    float2 f2; f2.x = lo; f2.y = hi;
    __hip_bfloat162 h2 = __float22bfloat162_rn(f2);
    unsigned int u;
    __builtin_memcpy(&u, &h2, 4);
    return u;
}

union bfrag {
    unsigned int u[4];
    short8v v;
};

// ---------------- Kernel 0: W f32 -> bf16, concat [q|k|v] rows -------------
__global__ __launch_bounds__(256) void wcvt_kernel(
    const float* __restrict__ Wq, const float* __restrict__ Wk,
    const float* __restrict__ Wv, unsigned short* __restrict__ wb)
{
    const int idx = blockIdx.x * 256 + threadIdx.x;   // 12288 threads x 8 elems
    const int e   = idx << 3;
    const int row = e >> 9, col = e & 511;
    const float* src = (row < 64) ? Wq : (row < 128) ? Wk : Wv;
    const float* p = src + (size_t)(row & 63) * DIMC + col;
    float4 a = *(const float4*)p;
    float4 b = *(const float4*)(p + 4);
    uint4 o;
    o.x = packbf(a.x, a.y); o.y = packbf(a.z, a.w);
    o.z = packbf(b.x, b.y); o.w = packbf(b.z, b.w);
    *(uint4*)(wb + e) = o;
}

// ---------------- Kernel A: MFMA QKV projection + rotary -------------------
// C^T form: C[h][t] = W(192x512) . x^T, mfma_f32_16x16x32_bf16.
// Block = 3 waves, wave w = matrix (0=q,1=k,2=v). Wave tile: 16 t x 64 h
// (t-tile halved vs round 4: grid 1024->2048 blocks, 3->6 waves/SIMD, to
// attack the latency-bound plateau).
__global__ __launch_bounds__(192) void qkv_mfma_kernel(
    const float* __restrict__ x,
    const unsigned short* __restrict__ wb,
    const float* __restrict__ fxr, const float* __restrict__ fxi,
    const float* __restrict__ fyr, const float* __restrict__ fyi,
    unsigned short* __restrict__ qo, unsigned short* __restrict__ ko,
    unsigned short* __restrict__ vt)
{
    const int tid = threadIdx.x;
    const int w   = tid >> 6;          // matrix: 0=q, 1=k, 2=v
    const int l   = tid & 63;
    const int q   = l & 15;
    const int g   = l >> 4;
    const int t0  = blockIdx.x << 4;   // 16 t-rows per block (global over B*T)

    f32x4 acc[4];
    #pragma unroll
    for (int ht = 0; ht < 4; ++ht) acc[ht] = (f32x4){0.f, 0.f, 0.f, 0.f};

    const unsigned short* wm = wb + ((size_t)w * 64) * DIMC;
    const float* xr0 = x + (size_t)(t0 + q) * DIMC + 8 * g;

    #pragma unroll 4
    for (int k0 = 0; k0 < DIMC; k0 += 32) {
        float4 a0 = *(const float4*)(xr0 + k0);
        float4 b0 = *(const float4*)(xr0 + k0 + 4);
        bfrag x0;
        x0.u[0] = packbf(a0.x, a0.y); x0.u[1] = packbf(a0.z, a0.w);
        x0.u[2] = packbf(b0.x, b0.y); x0.u[3] = packbf(b0.z, b0.w);

        short8v wf[4];
        #pragma unroll
        for (int ht = 0; ht < 4; ++ht)
            wf[ht] = *(const short8v*)(wm + (size_t)(16 * ht + q) * DIMC + k0 + 8 * g);

        #pragma unroll
        for (int ht = 0; ht < 4; ++ht)
            acc[ht] = __builtin_amdgcn_mfma_f32_16x16x32_bf16(wf[ht], x0.v, acc[ht], 0, 0, 0);
    }

    const float qscale = 1.4426950408889634f / 22.627416997969522f; // log2e/sqrt(512)
    const int trow = t0 + q;
    const int tl   = trow & (TT - 1);
    if (w == 2) {
        const int b = trow >> 11;
        #pragma unroll
        for (int ht = 0; ht < 4; ++ht) {
            const int d = 16 * ht + 4 * g;
            #pragma unroll
            for (int r = 0; r < 4; ++r)
                vt[((size_t)(b * HEADH) + d + r) * TT + tl] = f2bf(acc[ht][r]);
        }
    } else {
        const float sc = (w == 0) ? qscale : 1.f;
        unsigned short* dst = ((w == 0) ? qo : ko) + (size_t)trow * HEADH;
        #pragma unroll
        for (int ht = 0; ht < 4; ++ht) {
            const int hbase = 16 * ht + 4 * g;
            const int half  = hbase >> 5;
            const float* frt = half ? fyr : fxr;
            const float* fit = half ? fyi : fxi;
            const int pi0 = (hbase & 31) >> 1;
            float fr0 = frt[tl * 16 + pi0],     fi0 = fit[tl * 16 + pi0];
            float fr1 = frt[tl * 16 + pi0 + 1], fi1 = fit[tl * 16 + pi0 + 1];
            float e0 = acc[ht][0] * fr0 - acc[ht][1] * fi0;
            float e1 = acc[ht][0] * fi0 + acc[ht][1] * fr0;
            float e2 = acc[ht][2] * fr1 - acc[ht][3] * fi1;
            float e3 = acc[ht][2] * fi1 + acc[ht][3] * fr1;
            uint2 ow;
            ow.x = packbf(e0 * sc, e1 * sc);
            ow.y = packbf(e2 * sc, e3 * sc);
            *(uint2*)(dst + hbase) = ow;
        }
    }
}

// ---------------- Kernel B: MFMA flash attention, 4-wave KV-split -----------
// Block = 4 waves; wave w handles kv range [w*512, w*512+512) for the SAME
// 16 q-rows. XCD-aware bijective swizzle: hardware round-robins workgroups
// across the 8 XCDs (xcd = blockIdx & 7), so batch b = (blockIdx&7) + 8*hi
// pins each batch's K/V (512 KB) to one XCD's L2 -> per-XCD working set
// 2 batches = 1 MB << 4 MB L2. (Round-4 regression: default order thrashed
// L2 with all 16 batches per XCD, FETCH 445 MB.)
__global__ __launch_bounds__(256, 8) void attn_mfma_kernel(
    const unsigned short* __restrict__ qws,   // [b][t][64] bf16, pre-scaled
    const unsigned short* __restrict__ kws,   // [b][t][64] bf16
    const unsigned short* __restrict__ vtw,   // [b][d][t]  bf16 (V^T)
    float* __restrict__ out)
{
    __shared__ unsigned int smem[4224];       // 16.5 KB (union: plds | o+ml)

    const int tid  = threadIdx.x;
    const int w    = tid >> 6;                // wave = kv quarter
    const int l    = tid & 63;
    const int q    = l & 15;
    const int g    = l >> 4;
    const int dd   = blockIdx.x;
    const int xcd  = dd & 7;
    const int slot = dd >> 3;                 // 0..255
    const int b    = xcd + ((slot >> 7) << 3);// batches xcd, xcd+8 on XCD xcd
    const int q0   = (slot & 127) << 4;
    const int swz  = (q & 7) << 2;            // XOR on word-index bits 2..4

    unsigned int* plds = smem + w * 512;      // 2KB per wave, private

    short8v qf[2];
    {
        const unsigned short* qp = qws + ((size_t)(b * TT + q0 + q)) * HEADH + 8 * g;
        qf[0] = *(const short8v*)(qp);
        qf[1] = *(const short8v*)(qp + 32);
    }

    f32x4 oacc[4];
    #pragma unroll
    for (int mt = 0; mt < 4; ++mt) oacc[mt] = (f32x4){0.f, 0.f, 0.f, 0.f};
    float m = -1e30f, lsum = 0.f;

    const unsigned short* kbase = kws + (size_t)b * TT * HEADH;
    const unsigned short* vbase = vtw + (size_t)b * HEADH * TT;

    const int kvbeg = w << 9;                 // w*512
    for (int kv0 = kvbeg; kv0 < kvbeg + 512; kv0 += 64) {
        f32x4 sacc[4];
        #pragma unroll
        for (int n = 0; n < 4; ++n) {
            const unsigned short* kp = kbase + (size_t)(kv0 + 16 * n + q) * HEADH + 8 * g;
            short8v k0 = *(const short8v*)(kp);
            short8v k1 = *(const short8v*)(kp + 32);
            sacc[n] = (f32x4){0.f, 0.f, 0.f, 0.f};
            sacc[n] = __builtin_amdgcn_mfma_f32_16x16x32_bf16(k0, qf[0], sacc[n], 0, 0, 0);
            sacc[n] = __builtin_amdgcn_mfma_f32_16x16x32_bf16(k1, qf[1], sacc[n], 0, 0, 0);
        }

        short8v vf[2][4];
        #pragma unroll
        for (int s = 0; s < 2; ++s)
            #pragma unroll
            for (int mt = 0; mt < 4; ++mt)
                vf[s][mt] = *(const short8v*)(vbase +
                    (size_t)(16 * mt + q) * TT + kv0 + 32 * s + 8 * g);

        float cmax = sacc[0][0];
        #pragma unroll
        for (int n = 0; n < 4; ++n)
            #pragma unroll
            for (int r = 0; r < 4; ++r) cmax = fmaxf(cmax, sacc[n][r]);
        cmax = fmaxf(cmax, __shfl_xor(cmax, 16));
        cmax = fmaxf(cmax, __shfl_xor(cmax, 32));
        const float mnew = fmaxf(m, cmax);

        float p[4][4];
        float psum = 0.f;
        #pragma unroll
        for (int n = 0; n < 4; ++n)
            #pragma unroll
            for (int r = 0; r < 4; ++r) {
                p[n][r] = exp2f(sacc[n][r] - mnew);
                psum += p[n][r];
            }
        psum += __shfl_xor(psum, 16);
        psum += __shfl_xor(psum, 32);

        const float sc = exp2f(m - mnew);
        if (__any(cmax > m)) {
            #pragma unroll
            for (int mt = 0; mt < 4; ++mt)
                #pragma unroll
                for (int r = 0; r < 4; ++r) oacc[mt][r] *= sc;
        }
        lsum = lsum * sc + psum;
        m = mnew;

        #pragma unroll
        for (int n = 0; n < 4; ++n) {
            uint2 wv;
            wv.x = packbf(p[n][0], p[n][1]);
            wv.y = packbf(p[n][2], p[n][3]);
            *(uint2*)&plds[q * 32 + ((8 * n + 2 * g) ^ swz)] = wv;
        }

        #pragma unroll
        for (int s = 0; s < 2; ++s) {
            short8v pb = *(const short8v*)&plds[q * 32 + ((16 * s + 4 * g) ^ swz)];
            #pragma unroll
            for (int mt = 0; mt < 4; ++mt)
                oacc[mt] = __builtin_amdgcn_mfma_f32_16x16x32_bf16(vf[s][mt], pb,
                                                                   oacc[mt], 0, 0, 0);
        }
    }

    // ---- combine the 4 KV-quarter partials through LDS ----
    __syncthreads();                           // all plds reads done
    float* o_f  = (float*)smem;                // [4][16][64]
    float* ml_f = o_f + 4096;                  // [4][2][16]
    #pragma unroll
    for (int mt = 0; mt < 4; ++mt)
        *(f32x4*)&o_f[(w * 16 + q) * 64 + 16 * mt + 4 * g] = oacc[mt];
    if (g == 0) {
        ml_f[w * 32 + q]      = m;
        ml_f[w * 32 + 16 + q] = lsum;
    }
    __syncthreads();

    const int cq = tid >> 4;                   // 0..15: q row
    const int ch = (tid & 15) << 2;            // 0..60: h group of 4
    float mw[4], lw[4];
    #pragma unroll
    for (int ww = 0; ww < 4; ++ww) {
        mw[ww] = ml_f[ww * 32 + cq];
        lw[ww] = ml_f[ww * 32 + 16 + cq];
    }
    float M = fmaxf(fmaxf(mw[0], mw[1]), fmaxf(mw[2], mw[3]));
    float den = 0.f;
    float num0 = 0.f, num1 = 0.f, num2 = 0.f, num3 = 0.f;
    #pragma unroll
    for (int ww = 0; ww < 4; ++ww) {
        float al = exp2f(mw[ww] - M);
        den += al * lw[ww];
        const float* ov = &o_f[(ww * 16 + cq) * 64 + ch];
        num0 += al * ov[0];
        num1 += al * ov[1];
        num2 += al * ov[2];
        num3 += al * ov[3];
    }
    const float inv = 1.f / den;
    float4 res = make_float4(num0 * inv, num1 * inv, num2 * inv, num3 * inv);
    *(float4*)(out + ((size_t)(b * TT + q0 + cq)) * HEADH + ch) = res;
}

extern "C" void kernel_launch(void* const* d_in, const int* in_sizes, int n_in,
                              void* d_out, int out_size, void* d_ws, size_t ws_size,
                              hipStream_t stream)
{
    const float* x   = (const float*)d_in[0];
    const float* Wq  = (const float*)d_in[1];
    const float* Wk  = (const float*)d_in[2];
    const float* Wv  = (const float*)d_in[3];
    const float* fxr = (const float*)d_in[4];
    const float* fxi = (const float*)d_in[5];
    const float* fyr = (const float*)d_in[6];
    const float* fyi = (const float*)d_in[7];
    float* out = (float*)d_out;

    unsigned short* qo = (unsigned short*)d_ws;                  // 4 MB
    unsigned short* ko = qo + (size_t)BB * TT * HEADH;           // 4 MB
    unsigned short* vt = ko + (size_t)BB * TT * HEADH;           // 4 MB
    unsigned short* wb = vt + (size_t)BB * TT * HEADH;           // 192 KB

    wcvt_kernel<<<48, 256, 0, stream>>>(Wq, Wk, Wv, wb);
    qkv_mfma_kernel<<<(BB * TT) / 16, 192, 0, stream>>>(x, wb, fxr, fxi, fyr, fyi,
                                                        qo, ko, vt);
    attn_mfma_kernel<<<BB * 128, 256, 0, stream>>>(qo, ko, vt, out);
}

// Round 6
// 140.734 us; speedup vs baseline: 2.2684x; 2.2684x over previous
//
#include <hip/hip_runtime.h>
#include <hip/hip_bf16.h>

#define BB 16
#define TT 2048
#define DIMC 512
#define HEADH 64

typedef __attribute__((ext_vector_type(8))) short short8v;   // 8 bf16 (4 VGPRs)
typedef __attribute__((ext_vector_type(4))) float f32x4;     // MFMA C/D

static __device__ __forceinline__ unsigned short f2bf(float f) {
    __hip_bfloat16 h = __float2bfloat16(f);          // RNE, native path
    unsigned short u;
    __builtin_memcpy(&u, &h, 2);
    return u;
}
static __device__ __forceinline__ unsigned int packbf(float lo, float hi) {
    float2 f2; f2.x = lo; f2.y = hi;
    __hip_bfloat162 h2 = __float22bfloat162_rn(f2);
    unsigned int u;
    __builtin_memcpy(&u, &h2, 4);
    return u;
}

union bfrag {
    unsigned int u[4];
    short8v v;
};

// ---------------- Kernel 0: W f32 -> bf16, concat [q|k|v] rows -------------
__global__ __launch_bounds__(256) void wcvt_kernel(
    const float* __restrict__ Wq, const float* __restrict__ Wk,
    const float* __restrict__ Wv, unsigned short* __restrict__ wb)
{
    const int idx = blockIdx.x * 256 + threadIdx.x;   // 12288 threads x 8 elems
    const int e   = idx << 3;
    const int row = e >> 9, col = e & 511;
    const float* src = (row < 64) ? Wq : (row < 128) ? Wk : Wv;
    const float* p = src + (size_t)(row & 63) * DIMC + col;
    float4 a = *(const float4*)p;
    float4 b = *(const float4*)(p + 4);
    uint4 o;
    o.x = packbf(a.x, a.y); o.y = packbf(a.z, a.w);
    o.z = packbf(b.x, b.y); o.w = packbf(b.z, b.w);
    *(uint4*)(wb + e) = o;
}

// ---------------- Kernel A: MFMA QKV projection + rotary (round-4 version) --
// C^T form: C[h][t] = W(192x512) . x^T, mfma_f32_16x16x32_bf16.
// Block = 3 waves, wave w = matrix (0=q,1=k,2=v). Wave tile: 32 t x 64 h.
// (Round-5's 16-row tile regressed qkv 40->60us: doubled W re-reads.)
__global__ __launch_bounds__(192) void qkv_mfma_kernel(
    const float* __restrict__ x,
    const unsigned short* __restrict__ wb,
    const float* __restrict__ fxr, const float* __restrict__ fxi,
    const float* __restrict__ fyr, const float* __restrict__ fyi,
    unsigned short* __restrict__ qo, unsigned short* __restrict__ ko,
    unsigned short* __restrict__ vt)
{
    const int tid = threadIdx.x;
    const int w   = tid >> 6;          // matrix: 0=q, 1=k, 2=v
    const int l   = tid & 63;
    const int q   = l & 15;
    const int g   = l >> 4;
    const int t0  = blockIdx.x << 5;   // 32 t-rows per block (global over B*T)

    f32x4 acc[2][4];
    #pragma unroll
    for (int i = 0; i < 2; ++i)
        #pragma unroll
        for (int ht = 0; ht < 4; ++ht) acc[i][ht] = (f32x4){0.f, 0.f, 0.f, 0.f};

    const unsigned short* wm = wb + ((size_t)w * 64) * DIMC;
    const float* xr0 = x + (size_t)(t0 + q) * DIMC + 8 * g;
    const float* xr1 = x + (size_t)(t0 + 16 + q) * DIMC + 8 * g;

    #pragma unroll 4
    for (int k0 = 0; k0 < DIMC; k0 += 32) {
        float4 a0 = *(const float4*)(xr0 + k0);
        float4 b0 = *(const float4*)(xr0 + k0 + 4);
        float4 a1 = *(const float4*)(xr1 + k0);
        float4 b1 = *(const float4*)(xr1 + k0 + 4);
        bfrag x0, x1;
        x0.u[0] = packbf(a0.x, a0.y); x0.u[1] = packbf(a0.z, a0.w);
        x0.u[2] = packbf(b0.x, b0.y); x0.u[3] = packbf(b0.z, b0.w);
        x1.u[0] = packbf(a1.x, a1.y); x1.u[1] = packbf(a1.z, a1.w);
        x1.u[2] = packbf(b1.x, b1.y); x1.u[3] = packbf(b1.z, b1.w);

        short8v wf[4];
        #pragma unroll
        for (int ht = 0; ht < 4; ++ht)
            wf[ht] = *(const short8v*)(wm + (size_t)(16 * ht + q) * DIMC + k0 + 8 * g);

        #pragma unroll
        for (int ht = 0; ht < 4; ++ht) {
            acc[0][ht] = __builtin_amdgcn_mfma_f32_16x16x32_bf16(wf[ht], x0.v, acc[0][ht], 0, 0, 0);
            acc[1][ht] = __builtin_amdgcn_mfma_f32_16x16x32_bf16(wf[ht], x1.v, acc[1][ht], 0, 0, 0);
        }
    }

    const float qscale = 1.4426950408889634f / 22.627416997969522f; // log2e/sqrt(512)
    #pragma unroll
    for (int tt2 = 0; tt2 < 2; ++tt2) {
        const int trow = t0 + 16 * tt2 + q;
        const int tl   = trow & (TT - 1);
        if (w == 2) {
            const int b = trow >> 11;
            #pragma unroll
            for (int ht = 0; ht < 4; ++ht) {
                const int d = 16 * ht + 4 * g;
                #pragma unroll
                for (int r = 0; r < 4; ++r)
                    vt[((size_t)(b * HEADH) + d + r) * TT + tl] = f2bf(acc[tt2][ht][r]);
            }
        } else {
            const float sc = (w == 0) ? qscale : 1.f;
            unsigned short* dst = ((w == 0) ? qo : ko) + (size_t)trow * HEADH;
            #pragma unroll
            for (int ht = 0; ht < 4; ++ht) {
                const int hbase = 16 * ht + 4 * g;
                const int half  = hbase >> 5;
                const float* frt = half ? fyr : fxr;
                const float* fit = half ? fyi : fxi;
                const int pi0 = (hbase & 31) >> 1;
                float fr0 = frt[tl * 16 + pi0],     fi0 = fit[tl * 16 + pi0];
                float fr1 = frt[tl * 16 + pi0 + 1], fi1 = fit[tl * 16 + pi0 + 1];
                float e0 = acc[tt2][ht][0] * fr0 - acc[tt2][ht][1] * fi0;
                float e1 = acc[tt2][ht][0] * fi0 + acc[tt2][ht][1] * fr0;
                float e2 = acc[tt2][ht][2] * fr1 - acc[tt2][ht][3] * fi1;
                float e3 = acc[tt2][ht][2] * fi1 + acc[tt2][ht][3] * fr1;
                uint2 ow;
                ow.x = packbf(e0 * sc, e1 * sc);
                ow.y = packbf(e2 * sc, e3 * sc);
                *(uint2*)(dst + hbase) = ow;
            }
        }
    }
}

// ---------------- Kernel B: MFMA flash attention -----------------------------
// Block = 4 waves, q-tile = 32 rows. Wave w sweeps KV quarter [w*512,+512)
// for TWO q-subtiles (q0, q0+16) sharing every K/V load -> demand halves.
// K is register double-buffered: next iter's K issues right after this
// iter's QK MFMAs consume it (~600cy of cover). V issues at iter head and
// is consumed ~600cy later (post QK + 2x softmax) -> naturally hidden.
// Epilogue: LDS combine of 4 KV-quarter partials for 32 rows.
__global__ __launch_bounds__(256, 3) void attn_mfma_kernel(
    const unsigned short* __restrict__ qws,   // [b][t][64] bf16, pre-scaled
    const unsigned short* __restrict__ kws,   // [b][t][64] bf16
    const unsigned short* __restrict__ vtw,   // [b][d][t]  bf16 (V^T)
    float* __restrict__ out)
{
    __shared__ unsigned int smem[8448];       // 33KB: plds[4][2][512] | o[4][32][64]+ml

    const int tid = threadIdx.x;
    const int w   = tid >> 6;                 // wave = kv quarter
    const int l   = tid & 63;
    const int q   = l & 15;
    const int g   = l >> 4;
    const int b   = blockIdx.x >> 6;
    const int q0  = (blockIdx.x & 63) << 5;
    const int swz = (q & 7) << 2;             // XOR on word-index bits 2..4

    unsigned int* pldsA = smem + w * 1024;    // 2KB per wave per subtile
    unsigned int* pldsB = pldsA + 512;

    short8v qfA[2], qfB[2];
    {
        const unsigned short* qp = qws + ((size_t)(b * TT + q0 + q)) * HEADH + 8 * g;
        qfA[0] = *(const short8v*)(qp);
        qfA[1] = *(const short8v*)(qp + 32);
        qfB[0] = *(const short8v*)(qp + 16 * HEADH);
        qfB[1] = *(const short8v*)(qp + 16 * HEADH + 32);
    }

    f32x4 oaccA[4], oaccB[4];
    #pragma unroll
    for (int mt = 0; mt < 4; ++mt) {
        oaccA[mt] = (f32x4){0.f, 0.f, 0.f, 0.f};
        oaccB[mt] = (f32x4){0.f, 0.f, 0.f, 0.f};
    }
    float mA = -1e30f, lA = 0.f, mB = -1e30f, lB = 0.f;

    const unsigned short* kbase = kws + (size_t)b * TT * HEADH;
    const unsigned short* vbase = vtw + (size_t)b * HEADH * TT;

    const int kvbeg = w << 9;                 // w*512, 8 iters of 64 rows

    short8v kc[8];                            // current K tile fragments
    {
        const unsigned short* kp = kbase + (size_t)(kvbeg + q) * HEADH + 8 * g;
        #pragma unroll
        for (int n = 0; n < 4; ++n) {
            kc[2 * n]     = *(const short8v*)(kp + n * 16 * HEADH);
            kc[2 * n + 1] = *(const short8v*)(kp + n * 16 * HEADH + 32);
        }
    }

    #pragma unroll
    for (int it = 0; it < 8; ++it) {
        const int kv0 = kvbeg + it * 64;

        // V for this iter: issued at head, consumed after QK + 2x softmax
        short8v vf[8];
        #pragma unroll
        for (int s = 0; s < 2; ++s)
            #pragma unroll
            for (int mt = 0; mt < 4; ++mt)
                vf[s * 4 + mt] = *(const short8v*)(vbase +
                    (size_t)(16 * mt + q) * TT + kv0 + 32 * s + 8 * g);

        // ---- QK for both subtiles (shared kc) ----
        f32x4 sA[4], sB[4];
        #pragma unroll
        for (int n = 0; n < 4; ++n) {
            sA[n] = (f32x4){0.f, 0.f, 0.f, 0.f};
            sA[n] = __builtin_amdgcn_mfma_f32_16x16x32_bf16(kc[2 * n],     qfA[0], sA[n], 0, 0, 0);
            sA[n] = __builtin_amdgcn_mfma_f32_16x16x32_bf16(kc[2 * n + 1], qfA[1], sA[n], 0, 0, 0);
            sB[n] = (f32x4){0.f, 0.f, 0.f, 0.f};
            sB[n] = __builtin_amdgcn_mfma_f32_16x16x32_bf16(kc[2 * n],     qfB[0], sB[n], 0, 0, 0);
            sB[n] = __builtin_amdgcn_mfma_f32_16x16x32_bf16(kc[2 * n + 1], qfB[1], sB[n], 0, 0, 0);
        }

        // ---- prefetch next iter's K (kc now dead; ~600cy until next use) ----
        if (it < 7) {
            const unsigned short* kp = kbase + (size_t)(kv0 + 64 + q) * HEADH + 8 * g;
            #pragma unroll
            for (int n = 0; n < 4; ++n) {
                kc[2 * n]     = *(const short8v*)(kp + n * 16 * HEADH);
                kc[2 * n + 1] = *(const short8v*)(kp + n * 16 * HEADH + 32);
            }
        }

        // ---- softmax A ----
        {
            float cmax = sA[0][0];
            #pragma unroll
            for (int n = 0; n < 4; ++n)
                #pragma unroll
                for (int r = 0; r < 4; ++r) cmax = fmaxf(cmax, sA[n][r]);
            cmax = fmaxf(cmax, __shfl_xor(cmax, 16));
            cmax = fmaxf(cmax, __shfl_xor(cmax, 32));
            const float mnew = fmaxf(mA, cmax);
            float p[4][4];
            float psum = 0.f;
            #pragma unroll
            for (int n = 0; n < 4; ++n)
                #pragma unroll
                for (int r = 0; r < 4; ++r) {
                    p[n][r] = exp2f(sA[n][r] - mnew);
                    psum += p[n][r];
                }
            psum += __shfl_xor(psum, 16);
            psum += __shfl_xor(psum, 32);
            const float sc = exp2f(mA - mnew);
            if (__any(cmax > mA)) {
                #pragma unroll
                for (int mt = 0; mt < 4; ++mt)
                    #pragma unroll
                    for (int r = 0; r < 4; ++r) oaccA[mt][r] *= sc;
            }
            lA = lA * sc + psum;
            mA = mnew;
            #pragma unroll
            for (int n = 0; n < 4; ++n) {
                uint2 wv;
                wv.x = packbf(p[n][0], p[n][1]);
                wv.y = packbf(p[n][2], p[n][3]);
                *(uint2*)&pldsA[q * 32 + ((8 * n + 2 * g) ^ swz)] = wv;
            }
        }
        // ---- softmax B ----
        {
            float cmax = sB[0][0];
            #pragma unroll
            for (int n = 0; n < 4; ++n)
                #pragma unroll
                for (int r = 0; r < 4; ++r) cmax = fmaxf(cmax, sB[n][r]);
            cmax = fmaxf(cmax, __shfl_xor(cmax, 16));
            cmax = fmaxf(cmax, __shfl_xor(cmax, 32));
            const float mnew = fmaxf(mB, cmax);
            float p[4][4];
            float psum = 0.f;
            #pragma unroll
            for (int n = 0; n < 4; ++n)
                #pragma unroll
                for (int r = 0; r < 4; ++r) {
                    p[n][r] = exp2f(sB[n][r] - mnew);
                    psum += p[n][r];
                }
            psum += __shfl_xor(psum, 16);
            psum += __shfl_xor(psum, 32);
            const float sc = exp2f(mB - mnew);
            if (__any(cmax > mB)) {
                #pragma unroll
                for (int mt = 0; mt < 4; ++mt)
                    #pragma unroll
                    for (int r = 0; r < 4; ++r) oaccB[mt][r] *= sc;
            }
            lB = lB * sc + psum;
            mB = mnew;
            #pragma unroll
            for (int n = 0; n < 4; ++n) {
                uint2 wv;
                wv.x = packbf(p[n][0], p[n][1]);
                wv.y = packbf(p[n][2], p[n][3]);
                *(uint2*)&pldsB[q * 32 + ((8 * n + 2 * g) ^ swz)] = wv;
            }
        }

        // ---- PV for both subtiles (shared vf) ----
        #pragma unroll
        for (int s = 0; s < 2; ++s) {
            short8v pbA = *(const short8v*)&pldsA[q * 32 + ((16 * s + 4 * g) ^ swz)];
            short8v pbB = *(const short8v*)&pldsB[q * 32 + ((16 * s + 4 * g) ^ swz)];
            #pragma unroll
            for (int mt = 0; mt < 4; ++mt) {
                oaccA[mt] = __builtin_amdgcn_mfma_f32_16x16x32_bf16(vf[s * 4 + mt], pbA,
                                                                    oaccA[mt], 0, 0, 0);
                oaccB[mt] = __builtin_amdgcn_mfma_f32_16x16x32_bf16(vf[s * 4 + mt], pbB,
                                                                    oaccB[mt], 0, 0, 0);
            }
        }
    }

    // ---- combine the 4 KV-quarter partials through LDS ----
    __syncthreads();                           // all plds reads done
    float* o_f  = (float*)smem;                // [4][32][64]
    float* ml_f = o_f + 8192;                  // [4][2][32]
    #pragma unroll
    for (int mt = 0; mt < 4; ++mt) {
        *(f32x4*)&o_f[((w * 32 + q) * 64) + 16 * mt + 4 * g]      = oaccA[mt];
        *(f32x4*)&o_f[((w * 32 + 16 + q) * 64) + 16 * mt + 4 * g] = oaccB[mt];
    }
    if (g == 0) {
        ml_f[w * 64 + q]           = mA;
        ml_f[w * 64 + 32 + q]      = lA;
        ml_f[w * 64 + 16 + q]      = mB;
        ml_f[w * 64 + 32 + 16 + q] = lB;
    }
    __syncthreads();

    const int cq = tid >> 3;                   // 0..31: q row
    const int ch = (tid & 7) << 3;             // 0..56: h group of 8
    float mw[4], lw[4];
    #pragma unroll
    for (int ww = 0; ww < 4; ++ww) {
        mw[ww] = ml_f[ww * 64 + cq];
        lw[ww] = ml_f[ww * 64 + 32 + cq];
    }
    float M = fmaxf(fmaxf(mw[0], mw[1]), fmaxf(mw[2], mw[3]));
    float den = 0.f;
    float num[8];
    #pragma unroll
    for (int j = 0; j < 8; ++j) num[j] = 0.f;
    #pragma unroll
    for (int ww = 0; ww < 4; ++ww) {
        float al = exp2f(mw[ww] - M);
        den += al * lw[ww];
        const float* ov = &o_f[(ww * 32 + cq) * 64 + ch];
        float4 v0 = *(const float4*)(ov);
        float4 v1 = *(const float4*)(ov + 4);
        num[0] += al * v0.x; num[1] += al * v0.y;
        num[2] += al * v0.z; num[3] += al * v0.w;
        num[4] += al * v1.x; num[5] += al * v1.y;
        num[6] += al * v1.z; num[7] += al * v1.w;
    }
    const float inv = 1.f / den;
    float* op = out + ((size_t)(b * TT + q0 + cq)) * HEADH + ch;
    *(float4*)(op)     = make_float4(num[0] * inv, num[1] * inv, num[2] * inv, num[3] * inv);
    *(float4*)(op + 4) = make_float4(num[4] * inv, num[5] * inv, num[6] * inv, num[7] * inv);
}

extern "C" void kernel_launch(void* const* d_in, const int* in_sizes, int n_in,
                              void* d_out, int out_size, void* d_ws, size_t ws_size,
                              hipStream_t stream)
{
    const float* x   = (const float*)d_in[0];
    const float* Wq  = (const float*)d_in[1];
    const float* Wk  = (const float*)d_in[2];
    const float* Wv  = (const float*)d_in[3];
    const float* fxr = (const float*)d_in[4];
    const float* fxi = (const float*)d_in[5];
    const float* fyr = (const float*)d_in[6];
    const float* fyi = (const float*)d_in[7];
    float* out = (float*)d_out;

    unsigned short* qo = (unsigned short*)d_ws;                  // 4 MB
    unsigned short* ko = qo + (size_t)BB * TT * HEADH;           // 4 MB
    unsigned short* vt = ko + (size_t)BB * TT * HEADH;           // 4 MB
    unsigned short* wb = vt + (size_t)BB * TT * HEADH;           // 192 KB

    wcvt_kernel<<<48, 256, 0, stream>>>(Wq, Wk, Wv, wb);
    qkv_mfma_kernel<<<(BB * TT) / 32, 192, 0, stream>>>(x, wb, fxr, fxi, fyr, fyi,
                                                        qo, ko, vt);
    attn_mfma_kernel<<<BB * 64, 256, 0, stream>>>(qo, ko, vt, out);
}

// Round 7
// 102.964 us; speedup vs baseline: 3.1004x; 1.3668x over previous
//
#include <hip/hip_runtime.h>
#include <hip/hip_bf16.h>

#define BB 16
#define TT 2048
#define DIMC 512
#define HEADH 64

typedef __attribute__((ext_vector_type(8))) short short8v;   // 8 bf16 (4 VGPRs)
typedef __attribute__((ext_vector_type(4))) float f32x4;     // MFMA C/D

static __device__ __forceinline__ unsigned short f2bf(float f) {
    __hip_bfloat16 h = __float2bfloat16(f);          // RNE, native path
    unsigned short u;
    __builtin_memcpy(&u, &h, 2);
    return u;
}
static __device__ __forceinline__ unsigned int packbf(float lo, float hi) {
    float2 f2; f2.x = lo; f2.y = hi;
    __hip_bfloat162 h2 = __float22bfloat162_rn(f2);
    unsigned int u;
    __builtin_memcpy(&u, &h2, 4);
    return u;
}
// async global->LDS, 16B per lane; LDS dest = base + lane*16 (linear)
static __device__ __forceinline__ void async_copy16(void* lds, const void* g) {
    __builtin_amdgcn_global_load_lds(
        (const __attribute__((address_space(1))) unsigned char*)g,
        (__attribute__((address_space(3))) unsigned char*)lds, 16, 0, 0);
}

union bfrag {
    unsigned int u[4];
    short8v v;
};

// ---------------- Kernel 0: W f32 -> bf16, concat [q|k|v] rows -------------
__global__ __launch_bounds__(256) void wcvt_kernel(
    const float* __restrict__ Wq, const float* __restrict__ Wk,
    const float* __restrict__ Wv, unsigned short* __restrict__ wb)
{
    const int idx = blockIdx.x * 256 + threadIdx.x;   // 12288 threads x 8 elems
    const int e   = idx << 3;
    const int row = e >> 9, col = e & 511;
    const float* src = (row < 64) ? Wq : (row < 128) ? Wk : Wv;
    const float* p = src + (size_t)(row & 63) * DIMC + col;
    float4 a = *(const float4*)p;
    float4 b = *(const float4*)(p + 4);
    uint4 o;
    o.x = packbf(a.x, a.y); o.y = packbf(a.z, a.w);
    o.z = packbf(b.x, b.y); o.w = packbf(b.z, b.w);
    *(uint4*)(wb + e) = o;
}

// ---------------- Kernel A: MFMA QKV projection + rotary -------------------
// C^T form: C[h][t] = W(192x512) . x^T, mfma_f32_16x16x32_bf16.
// Block = 3 waves, wave w = matrix (0=q,1=k,2=v). Wave tile: 32 t x 64 h.
// Round 7: 1-deep software prefetch of x and W for the next k0 step.
__global__ __launch_bounds__(192) void qkv_mfma_kernel(
    const float* __restrict__ x,
    const unsigned short* __restrict__ wb,
    const float* __restrict__ fxr, const float* __restrict__ fxi,
    const float* __restrict__ fyr, const float* __restrict__ fyi,
    unsigned short* __restrict__ qo, unsigned short* __restrict__ ko,
    unsigned short* __restrict__ vt)
{
    const int tid = threadIdx.x;
    const int w   = tid >> 6;          // matrix: 0=q, 1=k, 2=v
    const int l   = tid & 63;
    const int q   = l & 15;
    const int g   = l >> 4;
    const int t0  = blockIdx.x << 5;   // 32 t-rows per block (global over B*T)

    f32x4 acc[2][4];
    #pragma unroll
    for (int i = 0; i < 2; ++i)
        #pragma unroll
        for (int ht = 0; ht < 4; ++ht) acc[i][ht] = (f32x4){0.f, 0.f, 0.f, 0.f};

    const unsigned short* wrow = wb + ((size_t)w * 64 + q) * DIMC + 8 * g;
    const float* xr0 = x + (size_t)(t0 + q) * DIMC + 8 * g;
    const float* xr1 = x + (size_t)(t0 + 16 + q) * DIMC + 8 * g;

    float4 a0 = *(const float4*)(xr0);
    float4 b0 = *(const float4*)(xr0 + 4);
    float4 a1 = *(const float4*)(xr1);
    float4 b1 = *(const float4*)(xr1 + 4);
    short8v wf0 = *(const short8v*)(wrow);
    short8v wf1 = *(const short8v*)(wrow + 16 * DIMC);
    short8v wf2 = *(const short8v*)(wrow + 32 * DIMC);
    short8v wf3 = *(const short8v*)(wrow + 48 * DIMC);

    #pragma unroll
    for (int kk = 0; kk < 16; ++kk) {
        const int k0 = kk * 32;
        float4 na0, nb0, na1, nb1;
        short8v nw0, nw1, nw2, nw3;
        if (kk < 15) {                 // prefetch next step (hides load latency)
            na0 = *(const float4*)(xr0 + k0 + 32);
            nb0 = *(const float4*)(xr0 + k0 + 36);
            na1 = *(const float4*)(xr1 + k0 + 32);
            nb1 = *(const float4*)(xr1 + k0 + 36);
            nw0 = *(const short8v*)(wrow + k0 + 32);
            nw1 = *(const short8v*)(wrow + 16 * DIMC + k0 + 32);
            nw2 = *(const short8v*)(wrow + 32 * DIMC + k0 + 32);
            nw3 = *(const short8v*)(wrow + 48 * DIMC + k0 + 32);
        }
        bfrag x0, x1;
        x0.u[0] = packbf(a0.x, a0.y); x0.u[1] = packbf(a0.z, a0.w);
        x0.u[2] = packbf(b0.x, b0.y); x0.u[3] = packbf(b0.z, b0.w);
        x1.u[0] = packbf(a1.x, a1.y); x1.u[1] = packbf(a1.z, a1.w);
        x1.u[2] = packbf(b1.x, b1.y); x1.u[3] = packbf(b1.z, b1.w);

        acc[0][0] = __builtin_amdgcn_mfma_f32_16x16x32_bf16(wf0, x0.v, acc[0][0], 0, 0, 0);
        acc[1][0] = __builtin_amdgcn_mfma_f32_16x16x32_bf16(wf0, x1.v, acc[1][0], 0, 0, 0);
        acc[0][1] = __builtin_amdgcn_mfma_f32_16x16x32_bf16(wf1, x0.v, acc[0][1], 0, 0, 0);
        acc[1][1] = __builtin_amdgcn_mfma_f32_16x16x32_bf16(wf1, x1.v, acc[1][1], 0, 0, 0);
        acc[0][2] = __builtin_amdgcn_mfma_f32_16x16x32_bf16(wf2, x0.v, acc[0][2], 0, 0, 0);
        acc[1][2] = __builtin_amdgcn_mfma_f32_16x16x32_bf16(wf2, x1.v, acc[1][2], 0, 0, 0);
        acc[0][3] = __builtin_amdgcn_mfma_f32_16x16x32_bf16(wf3, x0.v, acc[0][3], 0, 0, 0);
        acc[1][3] = __builtin_amdgcn_mfma_f32_16x16x32_bf16(wf3, x1.v, acc[1][3], 0, 0, 0);

        if (kk < 15) {
            a0 = na0; b0 = nb0; a1 = na1; b1 = nb1;
            wf0 = nw0; wf1 = nw1; wf2 = nw2; wf3 = nw3;
        }
    }

    const float qscale = 1.4426950408889634f / 22.627416997969522f; // log2e/sqrt(512)
    #pragma unroll
    for (int tt2 = 0; tt2 < 2; ++tt2) {
        const int trow = t0 + 16 * tt2 + q;
        const int tl   = trow & (TT - 1);
        if (w == 2) {
            const int b = trow >> 11;
            #pragma unroll
            for (int ht = 0; ht < 4; ++ht) {
                const int d = 16 * ht + 4 * g;
                #pragma unroll
                for (int r = 0; r < 4; ++r)
                    vt[((size_t)(b * HEADH) + d + r) * TT + tl] = f2bf(acc[tt2][ht][r]);
            }
        } else {
            const float sc = (w == 0) ? qscale : 1.f;
            unsigned short* dst = ((w == 0) ? qo : ko) + (size_t)trow * HEADH;
            #pragma unroll
            for (int ht = 0; ht < 4; ++ht) {
                const int hbase = 16 * ht + 4 * g;
                const int half  = hbase >> 5;
                const float* frt = half ? fyr : fxr;
                const float* fit = half ? fyi : fxi;
                const int pi0 = (hbase & 31) >> 1;
                float fr0 = frt[tl * 16 + pi0],     fi0 = fit[tl * 16 + pi0];
                float fr1 = frt[tl * 16 + pi0 + 1], fi1 = fit[tl * 16 + pi0 + 1];
                float e0 = acc[tt2][ht][0] * fr0 - acc[tt2][ht][1] * fi0;
                float e1 = acc[tt2][ht][0] * fi0 + acc[tt2][ht][1] * fr0;
                float e2 = acc[tt2][ht][2] * fr1 - acc[tt2][ht][3] * fi1;
                float e3 = acc[tt2][ht][2] * fi1 + acc[tt2][ht][3] * fr1;
                uint2 ow;
                ow.x = packbf(e0 * sc, e1 * sc);
                ow.y = packbf(e2 * sc, e3 * sc);
                *(uint2*)(dst + hbase) = ow;
            }
        }
    }
}

// ---------------- Kernel B: MFMA flash attention, q-split + LDS staging -----
// Block = 4 waves x 16 q-rows (q-tile 64). Full KV sweep, tiles of 64.
// K tile [64 kv][64 d] and V^T tile [64 d][64 t] staged bf16 in LDS via
// global_load_lds (16B/lane), double-buffered. XOR-swizzle slot = c16^(row&7)
// applied by PRE-SWIZZLING the per-lane global source (linear LDS dest);
// reads apply the same XOR -> conflict-free b128 (uniform 8/bank).
// One __syncthreads per iter: [stage nxt][read cur + compute][barrier].
//  - barrier's implicit vmcnt(0) makes nxt ready for the next iter
//  - reads of cur complete before barrier -> safe to overwrite cur after it
// No cross-wave combine: each wave owns complete output rows.
__global__ __launch_bounds__(256, 2) void attn_mfma_kernel(
    const unsigned short* __restrict__ qws,   // [b][t][64] bf16, pre-scaled
    const unsigned short* __restrict__ kws,   // [b][t][64] bf16
    const unsigned short* __restrict__ vtw,   // [b][d][t]  bf16 (V^T)
    float* __restrict__ out)
{
    __shared__ unsigned char smem[40960];     // K dbuf 16K | V dbuf 16K | plds 8K

    const int tid = threadIdx.x;
    const int w   = tid >> 6;                 // wave -> q-subtile
    const int l   = tid & 63;
    const int q   = l & 15;
    const int g   = l >> 4;
    const int b   = blockIdx.x >> 5;
    const int q0  = (blockIdx.x & 31) << 6;   // 64 q-rows per block
    const int qw  = q0 + 16 * w;              // this wave's q base
    const int rx  = q & 7;                    // read-side swizzle
    const int swz = (q & 7) << 2;             // plds swizzle (verified r2-r6)

    // staging lane constants: dest slot l&7 of row l>>3 holds logical col
    // block (l&7)^(l>>3)  [involution]
    const int rl = l >> 3;
    const int sl = (l & 7) ^ rl;

    unsigned int* pldsw = (unsigned int*)(smem + 32768 + (w << 11));

    const unsigned short* kbase = kws + (size_t)b * TT * HEADH;
    const unsigned short* vbase = vtw + (size_t)b * HEADH * TT;

    // per-lane pre-swizzled global sources; wave w stages chunks 2w, 2w+1
    const unsigned short* ksrc0 = kbase + (size_t)(16 * w + rl) * HEADH + 8 * sl;
    const unsigned short* ksrc1 = kbase + (size_t)(16 * w + 8 + rl) * HEADH + 8 * sl;
    const unsigned short* vsrc0 = vbase + (size_t)(16 * w + rl) * TT + 8 * sl;
    const unsigned short* vsrc1 = vbase + (size_t)(16 * w + 8 + rl) * TT + 8 * sl;

#define STAGE_TILE(bufsel, kv)  do {                                          \
        unsigned char* kd = smem + (bufsel) * 8192 + (w << 11);               \
        unsigned char* vd = smem + 16384 + (bufsel) * 8192 + (w << 11);       \
        async_copy16(kd,        ksrc0 + (size_t)(kv) * HEADH);                \
        async_copy16(kd + 1024, ksrc1 + (size_t)(kv) * HEADH);                \
        async_copy16(vd,        vsrc0 + (kv));                                \
        async_copy16(vd + 1024, vsrc1 + (kv));                                \
    } while (0)

    short8v qf0, qf1;
    {
        const unsigned short* qp = qws + ((size_t)(b * TT + qw + q)) * HEADH + 8 * g;
        qf0 = *(const short8v*)(qp);
        qf1 = *(const short8v*)(qp + 32);
    }

    f32x4 oacc[4];
    #pragma unroll
    for (int mt = 0; mt < 4; ++mt) oacc[mt] = (f32x4){0.f, 0.f, 0.f, 0.f};
    float m = -1e30f, lsum = 0.f;

    STAGE_TILE(0, 0);
    __syncthreads();                          // tile 0 resident

    int cur = 0;
    for (int it = 0; it < 32; ++it) {
        if (it < 31) STAGE_TILE(cur ^ 1, (it + 1) << 6);

        const unsigned char* kb = smem + cur * 8192;
        const unsigned char* vb = smem + 16384 + cur * 8192;

        // ---- QK^T from LDS ----
        f32x4 sacc[4];
        #pragma unroll
        for (int n = 0; n < 4; ++n) {
            const int r = 16 * n + q;
            const short8v k0 = *(const short8v*)(kb + r * 128 + ((g ^ rx) << 4));
            const short8v k1 = *(const short8v*)(kb + r * 128 + (((4 + g) ^ rx) << 4));
            f32x4 z = (f32x4){0.f, 0.f, 0.f, 0.f};
            z = __builtin_amdgcn_mfma_f32_16x16x32_bf16(k0, qf0, z, 0, 0, 0);
            z = __builtin_amdgcn_mfma_f32_16x16x32_bf16(k1, qf1, z, 0, 0, 0);
            sacc[n] = z;
        }

        // ---- online softmax (lane owns q-row qw + (l&15)) ----
        float cmax = sacc[0][0];
        #pragma unroll
        for (int n = 0; n < 4; ++n)
            #pragma unroll
            for (int r = 0; r < 4; ++r) cmax = fmaxf(cmax, sacc[n][r]);
        cmax = fmaxf(cmax, __shfl_xor(cmax, 16));
        cmax = fmaxf(cmax, __shfl_xor(cmax, 32));
        const float mnew = fmaxf(m, cmax);

        float p[4][4];
        float psum = 0.f;
        #pragma unroll
        for (int n = 0; n < 4; ++n)
            #pragma unroll
            for (int r = 0; r < 4; ++r) {
                p[n][r] = exp2f(sacc[n][r] - mnew);
                psum += p[n][r];
            }
        psum += __shfl_xor(psum, 16);
        psum += __shfl_xor(psum, 32);

        const float sc = exp2f(m - mnew);
        if (__any(cmax > m)) {
            #pragma unroll
            for (int mt = 0; mt < 4; ++mt)
                #pragma unroll
                for (int r = 0; r < 4; ++r) oacc[mt][r] *= sc;
        }
        lsum = lsum * sc + psum;
        m = mnew;

        // ---- P^T -> bf16 -> per-wave swizzled LDS ----
        #pragma unroll
        for (int n = 0; n < 4; ++n) {
            uint2 wv;
            wv.x = packbf(p[n][0], p[n][1]);
            wv.y = packbf(p[n][2], p[n][3]);
            *(uint2*)&pldsw[q * 32 + ((8 * n + 2 * g) ^ swz)] = wv;
        }

        // ---- PV: out^T += V^T . P^T (V from LDS) ----
        #pragma unroll
        for (int s = 0; s < 2; ++s) {
            const short8v pb = *(const short8v*)&pldsw[q * 32 + ((16 * s + 4 * g) ^ swz)];
            #pragma unroll
            for (int mt = 0; mt < 4; ++mt) {
                const int d = 16 * mt + q;
                const short8v vfr = *(const short8v*)(vb + d * 128 + ((((s << 2) + g) ^ rx) << 4));
                oacc[mt] = __builtin_amdgcn_mfma_f32_16x16x32_bf16(vfr, pb, oacc[mt], 0, 0, 0);
            }
        }

        __syncthreads();                      // nxt resident; cur reads done
        cur ^= 1;
    }

    // ---- normalize + store: oacc[mt][r] = out[qw+q][16mt+4g+r] ----
    const float inv = 1.f / lsum;
    float* op = out + ((size_t)(b * TT + qw + q)) * HEADH;
    #pragma unroll
    for (int mt = 0; mt < 4; ++mt) {
        float4 v4 = make_float4(oacc[mt][0] * inv, oacc[mt][1] * inv,
                                oacc[mt][2] * inv, oacc[mt][3] * inv);
        *(float4*)(op + 16 * mt + 4 * g) = v4;
    }
#undef STAGE_TILE
}

extern "C" void kernel_launch(void* const* d_in, const int* in_sizes, int n_in,
                              void* d_out, int out_size, void* d_ws, size_t ws_size,
                              hipStream_t stream)
{
    const float* x   = (const float*)d_in[0];
    const float* Wq  = (const float*)d_in[1];
    const float* Wk  = (const float*)d_in[2];
    const float* Wv  = (const float*)d_in[3];
    const float* fxr = (const float*)d_in[4];
    const float* fxi = (const float*)d_in[5];
    const float* fyr = (const float*)d_in[6];
    const float* fyi = (const float*)d_in[7];
    float* out = (float*)d_out;

    unsigned short* qo = (unsigned short*)d_ws;                  // 4 MB
    unsigned short* ko = qo + (size_t)BB * TT * HEADH;           // 4 MB
    unsigned short* vt = ko + (size_t)BB * TT * HEADH;           // 4 MB
    unsigned short* wb = vt + (size_t)BB * TT * HEADH;           // 192 KB

    wcvt_kernel<<<48, 256, 0, stream>>>(Wq, Wk, Wv, wb);
    qkv_mfma_kernel<<<(BB * TT) / 32, 192, 0, stream>>>(x, wb, fxr, fxi, fyr, fyi,
                                                        qo, ko, vt);
    attn_mfma_kernel<<<BB * 32, 256, 0, stream>>>(qo, ko, vt, out);
}